// Round 1
// baseline (435.485 us; speedup 1.0000x reference)
//
#include <hip/hip_runtime.h>

// Problem: B=2048, C=16, S=2000, fp32.
// Reference collapses: softmax rows sum to 1 over m, so
// einsum('bcs,bcm->bcs', x, score) == x exactly. The kernel is therefore
// out = LN_c(Wp @ x[b,:,s] + bp) * gp + hp, a pure streaming op:
// 262 MB in + 262 MB out -> ~83 us roofline @ 6.3 TB/s achievable.
//
// R1 change vs 456.5us baseline: float4 -> float2 per-thread tile.
// Rationale: float4 tile holds 32 float4 (=128 VGPR) of live data ->
// ~160 VGPR -> ~3 waves/SIMD; too little memory-level parallelism to
// saturate HBM (measured 1.15 TB/s = 18% of achievable). float2 halves
// live registers (~96 VGPR, launch_bounds caps at 128) -> ~5 waves/SIMD,
// 2x the waves in flight. Loads stay coalesced at 8B/lane = 512B/instr.
// Streaming loads/stores are nontemporal (zero reuse, don't thrash L2).

#define NC 16          // channels
#define NS 2000        // sequence
#define SV2 (NS / 2)   // 1000 float2 per (b,c) row
#define EPS 1e-5f
#define BLK 256

typedef float f32x2 __attribute__((ext_vector_type(2)));

__global__ __launch_bounds__(BLK, 4) void chanattn_fused(
    const float* __restrict__ x,
    const float* __restrict__ Wp,
    const float* __restrict__ bp,
    const float* __restrict__ gp,
    const float* __restrict__ hp,
    float* __restrict__ out,
    unsigned total)        // B * SV2
{
    // Params in LDS, W transposed: sW[cp][c] = Wp[c][cp]. All lanes read the
    // same address -> LDS broadcast, conflict-free.
    __shared__ float sW[NC * NC];
    __shared__ float sb[NC], sg[NC], sh[NC];
    const int tid = threadIdx.x;
    if (tid < NC * NC) sW[(tid & (NC - 1)) * NC + (tid >> 4)] = Wp[tid];
    if (tid < NC) { sb[tid] = bp[tid]; sg[tid] = gp[tid]; sh[tid] = hp[tid]; }
    __syncthreads();

    const unsigned t = blockIdx.x * BLK + tid;
    if (t >= total) return;
    const unsigned b  = t / SV2;       // const-division -> magic mul
    const unsigned s2 = t - b * SV2;

    const f32x2* __restrict__ px = (const f32x2*)x   + (size_t)b * (NC * SV2) + s2;
    f32x2*       __restrict__ po = (f32x2*)out       + (size_t)b * (NC * SV2) + s2;

    // 16 independent nontemporal loads in flight per wave (512B each,
    // perfectly coalesced).
    f32x2 xv[NC];
#pragma unroll
    for (int c = 0; c < NC; ++c)
        xv[c] = __builtin_nontemporal_load(&px[c * SV2]);

    // y[c] = bp[c] + sum_cp Wp[c][cp] * x[cp]   (2 positions at once)
    f32x2 y[NC];
#pragma unroll
    for (int c = 0; c < NC; ++c) {
        const float bb = sb[c];
        y[c].x = bb; y[c].y = bb;
    }
#pragma unroll
    for (int cp = 0; cp < NC; ++cp) {
        const f32x2 xc = xv[cp];
#pragma unroll
        for (int c = 0; c < NC; ++c) {
            const float w = sW[cp * NC + c];
            y[c].x = fmaf(w, xc.x, y[c].x);
            y[c].y = fmaf(w, xc.y, y[c].y);
        }
    }

    // LayerNorm over the 16 channels, per position (two-pass, in registers).
    float sx = 0.f, sy = 0.f;
#pragma unroll
    for (int c = 0; c < NC; ++c) { sx += y[c].x; sy += y[c].y; }
    const float inv = 1.0f / NC;
    const float mux = sx * inv, muy = sy * inv;

    float vx = 0.f, vy = 0.f;
#pragma unroll
    for (int c = 0; c < NC; ++c) {
        const float dx = y[c].x - mux, dy = y[c].y - muy;
        vx = fmaf(dx, dx, vx);
        vy = fmaf(dy, dy, vy);
    }
    const float rx = rsqrtf(vx * inv + EPS);
    const float ry = rsqrtf(vy * inv + EPS);

#pragma unroll
    for (int c = 0; c < NC; ++c) {
        const float g = sg[c], h = sh[c];
        f32x2 o;
        o.x = fmaf((y[c].x - mux) * rx, g, h);
        o.y = fmaf((y[c].y - muy) * ry, g, h);
        __builtin_nontemporal_store(o, &po[c * SV2]);
    }
}

extern "C" void kernel_launch(void* const* d_in, const int* in_sizes, int n_in,
                              void* d_out, int out_size, void* d_ws, size_t ws_size,
                              hipStream_t stream) {
    // setup_inputs order: x, Wq, bq, gq, hq, Wk, bk, gk, hk, Wp, bp, gp, hp
    const float* x  = (const float*)d_in[0];
    const float* Wp = (const float*)d_in[9];
    const float* bp = (const float*)d_in[10];
    const float* gp = (const float*)d_in[11];
    const float* hp = (const float*)d_in[12];
    float* out = (float*)d_out;

    const unsigned B = (unsigned)(in_sizes[0] / (NC * NS));  // 2048
    const unsigned total = B * SV2;                           // 2,048,000
    const unsigned grid = (total + BLK - 1) / BLK;            // 8000
    chanattn_fused<<<grid, BLK, 0, stream>>>(x, Wp, bp, gp, hp, out, total);
}